// Round 1
// baseline (2629.601 us; speedup 1.0000x reference)
//
#include <hip/hip_runtime.h>

#define N_USERS 200000
#define N_ITEMS 50000
#define NTOT    (N_USERS + N_ITEMS)
#define DIM     64
#define BATCH   4096

// One 64-lane wave per edge; lane = dim. Edge index is wave-uniform so
// rows/cols/vals loads are broadcast; gather + atomic scatter are coalesced.
__global__ void spmm_scatter(const float* __restrict__ x,
                             const int* __restrict__ rows,
                             const int* __restrict__ cols,
                             const float* __restrict__ vals,
                             float* __restrict__ y, int nE) {
    const int lane = threadIdx.x & 63;
    const int wid  = blockIdx.x * (blockDim.x >> 6) + (threadIdx.x >> 6);
    const int nw   = gridDim.x * (blockDim.x >> 6);
    for (int e = wid; e < nE; e += nw) {
        const int   r = rows[e];
        const int   c = cols[e];
        const float v = vals[e];
        const float xv = x[(size_t)c * DIM + lane];
        atomicAdd(&y[(size_t)r * DIM + lane], v * xv);
    }
}

// Write init_* sections (3..5) and seed final_* sections (0..2) with the
// layer-0 (embedding) term of the layer-mean.
__global__ void init_out(const float* __restrict__ emb,
                         const int* __restrict__ users,
                         const int* __restrict__ pos,
                         const int* __restrict__ neg,
                         float* __restrict__ out) {
    const int t = blockIdx.x * blockDim.x + threadIdx.x;
    const int lane = t & 63;
    const int w = t >> 6;
    if (w >= 3 * BATCH) return;
    const int s = w / BATCH;
    const int j = w - s * BATCH;
    const int row = (s == 0) ? users[j]
                  : (s == 1) ? pos[j] + N_USERS
                             : neg[j] + N_USERS;
    const float v = emb[(size_t)row * DIM + lane];
    out[(size_t)(s * BATCH + j) * DIM + lane] = v;        // final_* accumulator
    out[(size_t)((s + 3) * BATCH + j) * DIM + lane] = v;  // init_* output
}

// Accumulate one propagation layer's gathered rows into the final_* sections.
__global__ void gather_add(const float* __restrict__ e,
                           const int* __restrict__ users,
                           const int* __restrict__ pos,
                           const int* __restrict__ neg,
                           float* __restrict__ out) {
    const int t = blockIdx.x * blockDim.x + threadIdx.x;
    const int lane = t & 63;
    const int w = t >> 6;
    if (w >= 3 * BATCH) return;
    const int s = w / BATCH;
    const int j = w - s * BATCH;
    const int row = (s == 0) ? users[j]
                  : (s == 1) ? pos[j] + N_USERS
                             : neg[j] + N_USERS;
    out[(size_t)(s * BATCH + j) * DIM + lane] += e[(size_t)row * DIM + lane];
}

// final_* = layer-sum / (N_LAYERS+1)
__global__ void scale_out(float* __restrict__ out) {
    const int t = blockIdx.x * blockDim.x + threadIdx.x;
    if (t < 3 * BATCH * DIM) out[t] *= 0.25f;
}

extern "C" void kernel_launch(void* const* d_in, const int* in_sizes, int n_in,
                              void* d_out, int out_size, void* d_ws, size_t ws_size,
                              hipStream_t stream) {
    const float* emb  = (const float*)d_in[0];
    const int*   rows = (const int*)d_in[1];
    const int*   cols = (const int*)d_in[2];
    const float* vals = (const float*)d_in[3];
    const int*   users = (const int*)d_in[4];
    const int*   pos   = (const int*)d_in[5];
    const int*   neg   = (const int*)d_in[6];
    float* out = (float*)d_out;

    const int nE = in_sizes[1];                 // 4,000,000 edges
    const size_t bufElems = (size_t)NTOT * DIM; // 16M floats = 64 MB
    float* bufA = (float*)d_ws;
    float* bufB = bufA + bufElems;

    const int gatherBlocks = (3 * BATCH * DIM + 255) / 256;
    const int spmmBlocks   = 2048;  // 8192 waves = full residency, grid-stride

    // layer 0 contribution + init_* outputs
    init_out<<<gatherBlocks, 256, 0, stream>>>(emb, users, pos, neg, out);

    // layer 1: embed -> bufA
    hipMemsetAsync(bufA, 0, bufElems * sizeof(float), stream);
    spmm_scatter<<<spmmBlocks, 256, 0, stream>>>(emb, rows, cols, vals, bufA, nE);
    gather_add<<<gatherBlocks, 256, 0, stream>>>(bufA, users, pos, neg, out);

    // layer 2: bufA -> bufB
    hipMemsetAsync(bufB, 0, bufElems * sizeof(float), stream);
    spmm_scatter<<<spmmBlocks, 256, 0, stream>>>(bufA, rows, cols, vals, bufB, nE);
    gather_add<<<gatherBlocks, 256, 0, stream>>>(bufB, users, pos, neg, out);

    // layer 3: bufB -> bufA
    hipMemsetAsync(bufA, 0, bufElems * sizeof(float), stream);
    spmm_scatter<<<spmmBlocks, 256, 0, stream>>>(bufB, rows, cols, vals, bufA, nE);
    gather_add<<<gatherBlocks, 256, 0, stream>>>(bufA, users, pos, neg, out);

    // mean over (N_LAYERS+1) layers
    scale_out<<<gatherBlocks, 256, 0, stream>>>(out);
}

// Round 2
// 1271.064 us; speedup vs baseline: 2.0688x; 2.0688x over previous
//
#include <hip/hip_runtime.h>

#define N_USERS 200000
#define N_ITEMS 50000
#define NTOT    (N_USERS + N_ITEMS)
#define DIM     64
#define BATCH   4096

#define SCAN_TPB 256
#define SCAN_PER_THREAD 16
#define SCAN_ELEMS (SCAN_TPB * SCAN_PER_THREAD)  // 4096 rows per scan block

// ---------------- CSR build ----------------

__global__ void edge_hist(const int* __restrict__ rows, int* __restrict__ cnt, int nE) {
    const int e = blockIdx.x * blockDim.x + threadIdx.x;
    if (e < nE) atomicAdd(&cnt[rows[e]], 1);
}

// d_inv_sqrt recompute variant (saves 16 MB of stored vals)
__global__ void make_dis(const int* __restrict__ cnt, float* __restrict__ dis, int n) {
    const int i = blockIdx.x * blockDim.x + threadIdx.x;
    if (i < n) dis[i] = rsqrtf((float)cnt[i] + 1e-9f);
}

__global__ void scan_partials(const int* __restrict__ cnt, int* __restrict__ bsum, int n) {
    __shared__ int sh[SCAN_TPB];
    const int t = threadIdx.x;
    const int base = blockIdx.x * SCAN_ELEMS + t * SCAN_PER_THREAD;
    int s = 0;
    #pragma unroll
    for (int k = 0; k < SCAN_PER_THREAD; ++k) {
        const int idx = base + k;
        if (idx < n) s += cnt[idx];
    }
    sh[t] = s;
    __syncthreads();
    for (int off = SCAN_TPB / 2; off > 0; off >>= 1) {
        if (t < off) sh[t] += sh[t + off];
        __syncthreads();
    }
    if (t == 0) bsum[blockIdx.x] = sh[0];
}

__global__ void scan_offsets(int* __restrict__ bsum, int nb) {
    if (blockIdx.x == 0 && threadIdx.x == 0) {
        int acc = 0;
        for (int i = 0; i < nb; ++i) { const int v = bsum[i]; bsum[i] = acc; acc += v; }
    }
}

// In-place: P holds per-row counts on entry, exclusive-prefix start offsets on exit.
__global__ void scan_final(int* __restrict__ P, const int* __restrict__ bsum, int n) {
    __shared__ int sh[SCAN_TPB];
    const int t = threadIdx.x;
    const int base = blockIdx.x * SCAN_ELEMS + t * SCAN_PER_THREAD;
    int local[SCAN_PER_THREAD];
    int s = 0;
    #pragma unroll
    for (int k = 0; k < SCAN_PER_THREAD; ++k) {
        const int idx = base + k;
        const int v = (idx < n) ? P[idx] : 0;
        local[k] = s;       // exclusive within thread
        s += v;
    }
    sh[t] = s;
    __syncthreads();
    int incl = s;
    for (int off = 1; off < SCAN_TPB; off <<= 1) {   // Hillis-Steele inclusive scan
        const int add = (t >= off) ? sh[t - off] : 0;
        __syncthreads();
        incl += add;
        sh[t] = incl;
        __syncthreads();
    }
    const int thOff = incl - s + bsum[blockIdx.x];   // exclusive across threads + block base
    #pragma unroll
    for (int k = 0; k < SCAN_PER_THREAD; ++k) {
        const int idx = base + k;
        if (idx < n) P[idx] = thOff + local[k];
    }
}

// Uses P itself as the fill cursor: after this, P[r] = end offset of row r
// (= start offset of row r+1), so SpMM reads beg = P[r-1], end = P[r].
template <bool SV>
__global__ void csr_fill(const int* __restrict__ rows, const int* __restrict__ cols,
                         const float* __restrict__ vals, int* __restrict__ P,
                         int* __restrict__ ccol, float* __restrict__ cval, int nE) {
    const int e = blockIdx.x * blockDim.x + threadIdx.x;
    if (e >= nE) return;
    const int r = rows[e];
    const int p = atomicAdd(&P[r], 1);
    ccol[p] = cols[e];
    if (SV) cval[p] = vals[e];
}

// ---------------- SpMM (gather, no atomics) ----------------
// One 64-lane wave per destination row; lane = dim. Edge metadata loads are
// wave-uniform (broadcast); x-gather and y-write are coalesced 256 B/wave.
template <bool SV>
__global__ __launch_bounds__(256) void spmm_csr(const float* __restrict__ x,
                                                const int* __restrict__ P,
                                                const int* __restrict__ ccol,
                                                const float* __restrict__ cval,
                                                const float* __restrict__ dis,
                                                float* __restrict__ y) {
    const int lane = threadIdx.x & 63;
    const int wid  = blockIdx.x * (blockDim.x >> 6) + (threadIdx.x >> 6);
    if (wid >= NTOT) return;
    const int beg = (wid == 0) ? 0 : P[wid - 1];
    const int end = P[wid];
    float acc = 0.f;
    int e = beg;
    for (; e + 2 <= end; e += 2) {          // unroll-2 for memory-level parallelism
        const int c0 = ccol[e], c1 = ccol[e + 1];
        const float w0 = SV ? cval[e]     : dis[c0];
        const float w1 = SV ? cval[e + 1] : dis[c1];
        const float x0 = x[(size_t)c0 * DIM + lane];
        const float x1 = x[(size_t)c1 * DIM + lane];
        acc += w0 * x0;
        acc += w1 * x1;
    }
    if (e < end) {
        const int c = ccol[e];
        const float w = SV ? cval[e] : dis[c];
        acc += w * x[(size_t)c * DIM + lane];
    }
    if (!SV) acc *= dis[wid];               // val = dis[r]*dis[c], dis[r] factored out
    y[(size_t)wid * DIM + lane] = acc;
}

// ---------------- atomic-scatter fallback (proven round-1 path) ----------------

__global__ void spmm_scatter(const float* __restrict__ x,
                             const int* __restrict__ rows,
                             const int* __restrict__ cols,
                             const float* __restrict__ vals,
                             float* __restrict__ y, int nE) {
    const int lane = threadIdx.x & 63;
    const int wid  = blockIdx.x * (blockDim.x >> 6) + (threadIdx.x >> 6);
    const int nw   = gridDim.x * (blockDim.x >> 6);
    for (int e = wid; e < nE; e += nw) {
        const int   r = rows[e];
        const int   c = cols[e];
        const float v = vals[e];
        atomicAdd(&y[(size_t)r * DIM + lane], v * x[(size_t)c * DIM + lane]);
    }
}

// ---------------- output assembly ----------------

__global__ void init_out(const float* __restrict__ emb,
                         const int* __restrict__ users,
                         const int* __restrict__ pos,
                         const int* __restrict__ neg,
                         float* __restrict__ out) {
    const int t = blockIdx.x * blockDim.x + threadIdx.x;
    const int lane = t & 63;
    const int w = t >> 6;
    if (w >= 3 * BATCH) return;
    const int s = w / BATCH;
    const int j = w - s * BATCH;
    const int row = (s == 0) ? users[j] : (s == 1) ? pos[j] + N_USERS : neg[j] + N_USERS;
    const float v = emb[(size_t)row * DIM + lane];
    out[(size_t)(s * BATCH + j) * DIM + lane] = v;        // final_* accumulator (layer 0)
    out[(size_t)((s + 3) * BATCH + j) * DIM + lane] = v;  // init_* output
}

// out = (out + e[row]) * scale   (scale=1 for mid layers, 0.25 for last)
__global__ void gather_addscale(const float* __restrict__ e,
                                const int* __restrict__ users,
                                const int* __restrict__ pos,
                                const int* __restrict__ neg,
                                float* __restrict__ out, float scale) {
    const int t = blockIdx.x * blockDim.x + threadIdx.x;
    const int lane = t & 63;
    const int w = t >> 6;
    if (w >= 3 * BATCH) return;
    const int s = w / BATCH;
    const int j = w - s * BATCH;
    const int row = (s == 0) ? users[j] : (s == 1) ? pos[j] + N_USERS : neg[j] + N_USERS;
    const size_t o = (size_t)(s * BATCH + j) * DIM + lane;
    out[o] = (out[o] + e[(size_t)row * DIM + lane]) * scale;
}

// ---------------- host ----------------

extern "C" void kernel_launch(void* const* d_in, const int* in_sizes, int n_in,
                              void* d_out, int out_size, void* d_ws, size_t ws_size,
                              hipStream_t stream) {
    const float* emb  = (const float*)d_in[0];
    const int*   rows = (const int*)d_in[1];
    const int*   cols = (const int*)d_in[2];
    const float* vals = (const float*)d_in[3];
    const int*   users = (const int*)d_in[4];
    const int*   pos   = (const int*)d_in[5];
    const int*   neg   = (const int*)d_in[6];
    float* out = (float*)d_out;

    const int nE = in_sizes[1];
    auto rup = [](size_t x) { return (x + 255) & ~(size_t)255; };
    const size_t szBuf = rup((size_t)NTOT * DIM * sizeof(float));   // 64 MB
    const size_t szCol = rup((size_t)nE * sizeof(int));             // 16 MB
    const size_t szVal = rup((size_t)nE * sizeof(float));           // 16 MB
    const size_t szP   = rup((size_t)NTOT * sizeof(int));           // 1 MB
    const size_t szDis = rup((size_t)NTOT * sizeof(float));         // 1 MB
    const size_t szBs  = rup(1024 * sizeof(int));
    const size_t needA = 2 * szBuf + szCol + szVal + szP + szBs;        // ~161 MB
    const size_t needB = 2 * szBuf + szCol + szP + szDis + szBs;        // ~146 MB

    char* w = (char*)d_ws;
    float* bufA = (float*)w; w += szBuf;
    float* bufB = (float*)w; w += szBuf;

    const int gatherBlocks = (3 * BATCH * DIM + 255) / 256;
    const int edgeBlocks   = (nE + 255) / 256;

    init_out<<<gatherBlocks, 256, 0, stream>>>(emb, users, pos, neg, out);

    if (ws_size >= needB) {
        // ---- CSR gather path ----
        const bool SV = (ws_size >= needA);   // store vals vs recompute d_inv_sqrt
        int*   ccol = (int*)w;   w += szCol;
        float* cval = nullptr;
        float* dis  = nullptr;
        if (SV) { cval = (float*)w; w += szVal; }
        int* P    = (int*)w; w += szP;
        int* bsum = (int*)w; w += szBs;
        if (!SV) { dis = (float*)w; w += szDis; }

        hipMemsetAsync(P, 0, (size_t)NTOT * sizeof(int), stream);
        edge_hist<<<edgeBlocks, 256, 0, stream>>>(rows, P, nE);
        if (!SV) make_dis<<<(NTOT + 255) / 256, 256, 0, stream>>>(P, dis, NTOT);
        const int nb = (NTOT + SCAN_ELEMS - 1) / SCAN_ELEMS;   // 62
        scan_partials<<<nb, SCAN_TPB, 0, stream>>>(P, bsum, NTOT);
        scan_offsets<<<1, 64, 0, stream>>>(bsum, nb);
        scan_final<<<nb, SCAN_TPB, 0, stream>>>(P, bsum, NTOT);
        if (SV) csr_fill<true ><<<edgeBlocks, 256, 0, stream>>>(rows, cols, vals, P, ccol, cval, nE);
        else    csr_fill<false><<<edgeBlocks, 256, 0, stream>>>(rows, cols, vals, P, ccol, cval, nE);

        const int spmmBlocks = (NTOT + 3) / 4;   // 4 waves/block, 1 row/wave
        #define SPMM(XIN, YOUT) \
            do { if (SV) spmm_csr<true ><<<spmmBlocks, 256, 0, stream>>>(XIN, P, ccol, cval, dis, YOUT); \
                 else    spmm_csr<false><<<spmmBlocks, 256, 0, stream>>>(XIN, P, ccol, cval, dis, YOUT); } while (0)

        SPMM(emb, bufA);
        gather_addscale<<<gatherBlocks, 256, 0, stream>>>(bufA, users, pos, neg, out, 1.0f);
        SPMM(bufA, bufB);
        gather_addscale<<<gatherBlocks, 256, 0, stream>>>(bufB, users, pos, neg, out, 1.0f);
        SPMM(bufB, bufA);
        gather_addscale<<<gatherBlocks, 256, 0, stream>>>(bufA, users, pos, neg, out, 0.25f);
        #undef SPMM
    } else {
        // ---- atomic fallback (round-1 path, known good within 128 MB) ----
        const size_t bufBytes = (size_t)NTOT * DIM * sizeof(float);
        const int spmmBlocks = 2048;
        hipMemsetAsync(bufA, 0, bufBytes, stream);
        spmm_scatter<<<spmmBlocks, 256, 0, stream>>>(emb, rows, cols, vals, bufA, nE);
        gather_addscale<<<gatherBlocks, 256, 0, stream>>>(bufA, users, pos, neg, out, 1.0f);
        hipMemsetAsync(bufB, 0, bufBytes, stream);
        spmm_scatter<<<spmmBlocks, 256, 0, stream>>>(bufA, rows, cols, vals, bufB, nE);
        gather_addscale<<<gatherBlocks, 256, 0, stream>>>(bufB, users, pos, neg, out, 1.0f);
        hipMemsetAsync(bufA, 0, bufBytes, stream);
        spmm_scatter<<<spmmBlocks, 256, 0, stream>>>(bufB, rows, cols, vals, bufA, nE);
        gather_addscale<<<gatherBlocks, 256, 0, stream>>>(bufA, users, pos, neg, out, 0.25f);
    }
}

// Round 3
// 917.794 us; speedup vs baseline: 2.8651x; 1.3849x over previous
//
#include <hip/hip_runtime.h>

#define N_USERS 200000
#define N_ITEMS 50000
#define NTOT    (N_USERS + N_ITEMS)
#define DIM     64
#define BATCH   4096

#define SCAN_TPB 256
#define SCAN_PER_THREAD 16
#define SCAN_ELEMS (SCAN_TPB * SCAN_PER_THREAD)  // 4096 rows per scan block

// ---------------- CSR build ----------------

// int4-vectorized histogram: 4 edges/thread
__global__ void edge_hist(const int* __restrict__ rows, int* __restrict__ cnt, int nE) {
    const int t = blockIdx.x * blockDim.x + threadIdx.x;
    const int base = t * 4;
    if (base + 4 <= nE) {
        const int4 r4 = *reinterpret_cast<const int4*>(rows + base);
        atomicAdd(&cnt[r4.x], 1);
        atomicAdd(&cnt[r4.y], 1);
        atomicAdd(&cnt[r4.z], 1);
        atomicAdd(&cnt[r4.w], 1);
    } else {
        for (int e = base; e < nE; ++e) atomicAdd(&cnt[rows[e]], 1);
    }
}

__global__ void make_dis(const int* __restrict__ cnt, float* __restrict__ dis, int n) {
    const int i = blockIdx.x * blockDim.x + threadIdx.x;
    if (i < n) dis[i] = rsqrtf((float)cnt[i] + 1e-9f);
}

__global__ void scan_partials(const int* __restrict__ cnt, int* __restrict__ bsum, int n) {
    __shared__ int sh[SCAN_TPB];
    const int t = threadIdx.x;
    const int base = blockIdx.x * SCAN_ELEMS + t * SCAN_PER_THREAD;
    int s = 0;
    #pragma unroll
    for (int k = 0; k < SCAN_PER_THREAD; ++k) {
        const int idx = base + k;
        if (idx < n) s += cnt[idx];
    }
    sh[t] = s;
    __syncthreads();
    for (int off = SCAN_TPB / 2; off > 0; off >>= 1) {
        if (t < off) sh[t] += sh[t + off];
        __syncthreads();
    }
    if (t == 0) bsum[blockIdx.x] = sh[0];
}

__global__ void scan_offsets(int* __restrict__ bsum, int nb) {
    if (blockIdx.x == 0 && threadIdx.x == 0) {
        int acc = 0;
        for (int i = 0; i < nb; ++i) { const int v = bsum[i]; bsum[i] = acc; acc += v; }
    }
}

// In-place: P holds per-row counts on entry, exclusive-prefix start offsets on exit.
__global__ void scan_final(int* __restrict__ P, const int* __restrict__ bsum, int n) {
    __shared__ int sh[SCAN_TPB];
    const int t = threadIdx.x;
    const int base = blockIdx.x * SCAN_ELEMS + t * SCAN_PER_THREAD;
    int local[SCAN_PER_THREAD];
    int s = 0;
    #pragma unroll
    for (int k = 0; k < SCAN_PER_THREAD; ++k) {
        const int idx = base + k;
        const int v = (idx < n) ? P[idx] : 0;
        local[k] = s;
        s += v;
    }
    sh[t] = s;
    __syncthreads();
    int incl = s;
    for (int off = 1; off < SCAN_TPB; off <<= 1) {
        const int add = (t >= off) ? sh[t - off] : 0;
        __syncthreads();
        incl += add;
        sh[t] = incl;
        __syncthreads();
    }
    const int thOff = incl - s + bsum[blockIdx.x];
    #pragma unroll
    for (int k = 0; k < SCAN_PER_THREAD; ++k) {
        const int idx = base + k;
        if (idx < n) P[idx] = thOff + local[k];
    }
}

// Packed scatter: one 8 B random write per edge instead of two 4 B writes.
// After this, P[r] = end offset of row r, so SpMM reads beg=P[r-1], end=P[r].
template <bool SV>
__global__ void csr_fill(const int* __restrict__ rows, const int* __restrict__ cols,
                         const float* __restrict__ vals, int* __restrict__ P,
                         int2* __restrict__ cpk, int* __restrict__ ccol, int nE) {
    const int e = blockIdx.x * blockDim.x + threadIdx.x;
    if (e >= nE) return;
    const int r = rows[e];
    const int p = atomicAdd(&P[r], 1);
    if (SV) cpk[p] = make_int2(cols[e], __float_as_int(vals[e]));
    else    ccol[p] = cols[e];
}

// ---------------- SpMM (gather, no atomics) ----------------
// One 64-lane wave per destination row; lane = dim. Edge metadata loads are
// wave-uniform (broadcast); x-gather and y-write are coalesced 256 B/wave.
template <bool SV>
__global__ __launch_bounds__(256) void spmm_csr(const float* __restrict__ x,
                                                const int* __restrict__ P,
                                                const int2* __restrict__ cpk,
                                                const int* __restrict__ ccol,
                                                const float* __restrict__ dis,
                                                float* __restrict__ y) {
    const int lane = threadIdx.x & 63;
    const int wid  = blockIdx.x * (blockDim.x >> 6) + (threadIdx.x >> 6);
    if (wid >= NTOT) return;
    const int beg = (wid == 0) ? 0 : P[wid - 1];
    const int end = P[wid];
    float acc = 0.f;
    int e = beg;
    for (; e + 4 <= end; e += 4) {   // unroll-4 for memory-level parallelism
        int   c0, c1, c2, c3;
        float w0, w1, w2, w3;
        if (SV) {
            const int2 p0 = cpk[e], p1 = cpk[e+1], p2 = cpk[e+2], p3 = cpk[e+3];
            c0 = p0.x; w0 = __int_as_float(p0.y);
            c1 = p1.x; w1 = __int_as_float(p1.y);
            c2 = p2.x; w2 = __int_as_float(p2.y);
            c3 = p3.x; w3 = __int_as_float(p3.y);
        } else {
            c0 = ccol[e]; c1 = ccol[e+1]; c2 = ccol[e+2]; c3 = ccol[e+3];
            w0 = dis[c0]; w1 = dis[c1]; w2 = dis[c2]; w3 = dis[c3];
        }
        const float x0 = x[(size_t)c0 * DIM + lane];
        const float x1 = x[(size_t)c1 * DIM + lane];
        const float x2 = x[(size_t)c2 * DIM + lane];
        const float x3 = x[(size_t)c3 * DIM + lane];
        acc += w0 * x0; acc += w1 * x1; acc += w2 * x2; acc += w3 * x3;
    }
    for (; e < end; ++e) {
        int c; float w;
        if (SV) { const int2 p = cpk[e]; c = p.x; w = __int_as_float(p.y); }
        else    { c = ccol[e]; w = dis[c]; }
        acc += w * x[(size_t)c * DIM + lane];
    }
    if (!SV) acc *= dis[wid];
    y[(size_t)wid * DIM + lane] = acc;
}

// ---------------- layer-3 sparse rows: compute ONLY the 12,288 sampled rows,
// fused with the final accumulate+scale into out. ----------------
template <bool SV>
__global__ __launch_bounds__(256) void spmm_rows_out(const float* __restrict__ x,
                                                     const int* __restrict__ P,
                                                     const int2* __restrict__ cpk,
                                                     const int* __restrict__ ccol,
                                                     const float* __restrict__ dis,
                                                     const int* __restrict__ users,
                                                     const int* __restrict__ pos,
                                                     const int* __restrict__ neg,
                                                     float* __restrict__ out) {
    const int lane = threadIdx.x & 63;
    const int wid  = blockIdx.x * (blockDim.x >> 6) + (threadIdx.x >> 6);
    if (wid >= 3 * BATCH) return;
    const int s = wid / BATCH;
    const int j = wid - s * BATCH;
    const int row = (s == 0) ? users[j] : (s == 1) ? pos[j] + N_USERS : neg[j] + N_USERS;
    const int beg = (row == 0) ? 0 : P[row - 1];
    const int end = P[row];
    float acc = 0.f;
    int e = beg;
    for (; e + 4 <= end; e += 4) {
        int   c0, c1, c2, c3;
        float w0, w1, w2, w3;
        if (SV) {
            const int2 p0 = cpk[e], p1 = cpk[e+1], p2 = cpk[e+2], p3 = cpk[e+3];
            c0 = p0.x; w0 = __int_as_float(p0.y);
            c1 = p1.x; w1 = __int_as_float(p1.y);
            c2 = p2.x; w2 = __int_as_float(p2.y);
            c3 = p3.x; w3 = __int_as_float(p3.y);
        } else {
            c0 = ccol[e]; c1 = ccol[e+1]; c2 = ccol[e+2]; c3 = ccol[e+3];
            w0 = dis[c0]; w1 = dis[c1]; w2 = dis[c2]; w3 = dis[c3];
        }
        acc += w0 * x[(size_t)c0 * DIM + lane];
        acc += w1 * x[(size_t)c1 * DIM + lane];
        acc += w2 * x[(size_t)c2 * DIM + lane];
        acc += w3 * x[(size_t)c3 * DIM + lane];
    }
    for (; e < end; ++e) {
        int c; float w;
        if (SV) { const int2 p = cpk[e]; c = p.x; w = __int_as_float(p.y); }
        else    { c = ccol[e]; w = dis[c]; }
        acc += w * x[(size_t)c * DIM + lane];
    }
    if (!SV) acc *= dis[row];
    const size_t o = (size_t)(s * BATCH + j) * DIM + lane;
    out[o] = (out[o] + acc) * 0.25f;   // mean over (N_LAYERS+1)
}

// ---------------- atomic-scatter fallback ----------------

__global__ void spmm_scatter(const float* __restrict__ x,
                             const int* __restrict__ rows,
                             const int* __restrict__ cols,
                             const float* __restrict__ vals,
                             float* __restrict__ y, int nE) {
    const int lane = threadIdx.x & 63;
    const int wid  = blockIdx.x * (blockDim.x >> 6) + (threadIdx.x >> 6);
    const int nw   = gridDim.x * (blockDim.x >> 6);
    for (int e = wid; e < nE; e += nw) {
        atomicAdd(&y[(size_t)rows[e] * DIM + lane], vals[e] * x[(size_t)cols[e] * DIM + lane]);
    }
}

// ---------------- output assembly ----------------

__global__ void init_out(const float* __restrict__ emb,
                         const int* __restrict__ users,
                         const int* __restrict__ pos,
                         const int* __restrict__ neg,
                         float* __restrict__ out) {
    const int t = blockIdx.x * blockDim.x + threadIdx.x;
    const int lane = t & 63;
    const int w = t >> 6;
    if (w >= 3 * BATCH) return;
    const int s = w / BATCH;
    const int j = w - s * BATCH;
    const int row = (s == 0) ? users[j] : (s == 1) ? pos[j] + N_USERS : neg[j] + N_USERS;
    const float v = emb[(size_t)row * DIM + lane];
    out[(size_t)(s * BATCH + j) * DIM + lane] = v;        // final_* accumulator (layer 0)
    out[(size_t)((s + 3) * BATCH + j) * DIM + lane] = v;  // init_* output
}

__global__ void gather_addscale(const float* __restrict__ e,
                                const int* __restrict__ users,
                                const int* __restrict__ pos,
                                const int* __restrict__ neg,
                                float* __restrict__ out, float scale) {
    const int t = blockIdx.x * blockDim.x + threadIdx.x;
    const int lane = t & 63;
    const int w = t >> 6;
    if (w >= 3 * BATCH) return;
    const int s = w / BATCH;
    const int j = w - s * BATCH;
    const int row = (s == 0) ? users[j] : (s == 1) ? pos[j] + N_USERS : neg[j] + N_USERS;
    const size_t o = (size_t)(s * BATCH + j) * DIM + lane;
    out[o] = (out[o] + e[(size_t)row * DIM + lane]) * scale;
}

// ---------------- host ----------------

extern "C" void kernel_launch(void* const* d_in, const int* in_sizes, int n_in,
                              void* d_out, int out_size, void* d_ws, size_t ws_size,
                              hipStream_t stream) {
    const float* emb  = (const float*)d_in[0];
    const int*   rows = (const int*)d_in[1];
    const int*   cols = (const int*)d_in[2];
    const float* vals = (const float*)d_in[3];
    const int*   users = (const int*)d_in[4];
    const int*   pos   = (const int*)d_in[5];
    const int*   neg   = (const int*)d_in[6];
    float* out = (float*)d_out;

    const int nE = in_sizes[1];
    auto rup = [](size_t x) { return (x + 255) & ~(size_t)255; };
    const size_t szBuf = rup((size_t)NTOT * DIM * sizeof(float));   // 64 MB
    const size_t szPk  = rup((size_t)nE * sizeof(int2));            // 32 MB
    const size_t szCol = rup((size_t)nE * sizeof(int));             // 16 MB
    const size_t szP   = rup((size_t)NTOT * sizeof(int));           // 1 MB
    const size_t szDis = rup((size_t)NTOT * sizeof(float));         // 1 MB
    const size_t szBs  = rup(1024 * sizeof(int));
    const size_t needA = 2 * szBuf + szPk + szP + szBs;             // ~161 MB (packed)
    const size_t needB = 2 * szBuf + szCol + szP + szDis + szBs;    // ~146 MB

    char* w = (char*)d_ws;
    float* bufA = (float*)w; w += szBuf;
    float* bufB = (float*)w; w += szBuf;

    const int gatherBlocks = (3 * BATCH * DIM + 255) / 256;
    const int edgeBlocks   = (nE + 255) / 256;

    init_out<<<gatherBlocks, 256, 0, stream>>>(emb, users, pos, neg, out);

    if (ws_size >= needB) {
        const bool SV = (ws_size >= needA);   // packed (col,val) vs recompute dis
        int2* cpk  = nullptr;
        int*  ccol = nullptr;
        float* dis = nullptr;
        if (SV) { cpk = (int2*)w; w += szPk; }
        else    { ccol = (int*)w; w += szCol; }
        int* P    = (int*)w; w += szP;
        int* bsum = (int*)w; w += szBs;
        if (!SV) { dis = (float*)w; w += szDis; }

        hipMemsetAsync(P, 0, (size_t)NTOT * sizeof(int), stream);
        edge_hist<<<(nE / 4 + 255) / 256, 256, 0, stream>>>(rows, P, nE);
        if (!SV) make_dis<<<(NTOT + 255) / 256, 256, 0, stream>>>(P, dis, NTOT);
        const int nb = (NTOT + SCAN_ELEMS - 1) / SCAN_ELEMS;   // 62
        scan_partials<<<nb, SCAN_TPB, 0, stream>>>(P, bsum, NTOT);
        scan_offsets<<<1, 64, 0, stream>>>(bsum, nb);
        scan_final<<<nb, SCAN_TPB, 0, stream>>>(P, bsum, NTOT);
        if (SV) csr_fill<true ><<<edgeBlocks, 256, 0, stream>>>(rows, cols, vals, P, cpk, ccol, nE);
        else    csr_fill<false><<<edgeBlocks, 256, 0, stream>>>(rows, cols, vals, P, cpk, ccol, nE);

        const int spmmBlocks = (NTOT + 3) / 4;   // 4 waves/block, 1 row/wave
        #define SPMM(XIN, YOUT) \
            do { if (SV) spmm_csr<true ><<<spmmBlocks, 256, 0, stream>>>(XIN, P, cpk, ccol, dis, YOUT); \
                 else    spmm_csr<false><<<spmmBlocks, 256, 0, stream>>>(XIN, P, cpk, ccol, dis, YOUT); } while (0)

        // layers 1,2: full SpMM (outputs needed as next layer's input)
        SPMM(emb, bufA);
        gather_addscale<<<gatherBlocks, 256, 0, stream>>>(bufA, users, pos, neg, out, 1.0f);
        SPMM(bufA, bufB);
        gather_addscale<<<gatherBlocks, 256, 0, stream>>>(bufB, users, pos, neg, out, 1.0f);
        #undef SPMM

        // layer 3: only the 12,288 sampled rows, fused with final accumulate+scale
        const int rowsBlocks = (3 * BATCH + 3) / 4;
        if (SV) spmm_rows_out<true ><<<rowsBlocks, 256, 0, stream>>>(bufB, P, cpk, ccol, dis, users, pos, neg, out);
        else    spmm_rows_out<false><<<rowsBlocks, 256, 0, stream>>>(bufB, P, cpk, ccol, dis, users, pos, neg, out);
    } else {
        // ---- atomic fallback ----
        const size_t bufBytes = (size_t)NTOT * DIM * sizeof(float);
        const int spmmBlocks = 2048;
        hipMemsetAsync(bufA, 0, bufBytes, stream);
        spmm_scatter<<<spmmBlocks, 256, 0, stream>>>(emb, rows, cols, vals, bufA, nE);
        gather_addscale<<<gatherBlocks, 256, 0, stream>>>(bufA, users, pos, neg, out, 1.0f);
        hipMemsetAsync(bufB, 0, bufBytes, stream);
        spmm_scatter<<<spmmBlocks, 256, 0, stream>>>(bufA, rows, cols, vals, bufB, nE);
        gather_addscale<<<gatherBlocks, 256, 0, stream>>>(bufB, users, pos, neg, out, 1.0f);
        hipMemsetAsync(bufA, 0, bufBytes, stream);
        spmm_scatter<<<spmmBlocks, 256, 0, stream>>>(bufB, rows, cols, vals, bufA, nE);
        gather_addscale<<<gatherBlocks, 256, 0, stream>>>(bufA, users, pos, neg, out, 0.25f);
    }
}

// Round 5
// 642.370 us; speedup vs baseline: 4.0936x; 1.4288x over previous
//
#include <hip/hip_runtime.h>

#define N_USERS 200000
#define N_ITEMS 50000
#define NTOT    (N_USERS + N_ITEMS)    // 250000
#define DIM     64
#define BATCH   4096

#define RB      256                    // rows per bucket
#define NB      ((NTOT + RB - 1) / RB) // 977 buckets
#define TILE    8192                   // edges per phase-A tile
#define CAP     15360                  // LDS-sortable entries/bucket (mean 10.2K items, +50 sd head)

// ---------------- build: coarse bucket histogram ----------------
__global__ void coarse_hist(const int* __restrict__ rows, int* __restrict__ bCnt, int nE) {
    __shared__ int h[NB];
    for (int b = threadIdx.x; b < NB; b += blockDim.x) h[b] = 0;
    __syncthreads();
    const int t  = blockIdx.x * blockDim.x + threadIdx.x;
    const int nT = gridDim.x * blockDim.x;
    const int n4 = nE >> 2;
    for (int i = t; i < n4; i += nT) {
        const int4 r4 = reinterpret_cast<const int4*>(rows)[i];
        atomicAdd(&h[r4.x >> 8], 1);
        atomicAdd(&h[r4.y >> 8], 1);
        atomicAdd(&h[r4.z >> 8], 1);
        atomicAdd(&h[r4.w >> 8], 1);
    }
    for (int e = (n4 << 2) + t; e < nE; e += nT) atomicAdd(&h[rows[e] >> 8], 1);
    __syncthreads();
    for (int b = threadIdx.x; b < NB; b += blockDim.x) {
        const int c = h[b];
        if (c) atomicAdd(&bCnt[b], c);
    }
}

// single-block scan of NB bucket counts -> bStart (exclusive, +total at [NB]), bCur copy
__global__ void bucket_scan(const int* __restrict__ bCnt, int* __restrict__ bStart,
                            int* __restrict__ bCur) {
    __shared__ int sc[1024];
    const int t = threadIdx.x;
    const int v = (t < NB) ? bCnt[t] : 0;
    sc[t] = v;
    __syncthreads();
    int incl = v;
    for (int s = 1; s < 1024; s <<= 1) {
        const int add = (t >= s) ? sc[t - s] : 0;
        __syncthreads();
        incl += add;
        sc[t] = incl;
        __syncthreads();
    }
    if (t < NB) {
        const int excl = incl - v;
        bStart[t] = excl;
        bCur[t]   = excl;
        if (t == NB - 1) bStart[NB] = incl;
    }
}

// ---------------- build: phase A — LDS-ranked multisplit into buckets ----------------
// entry = col(18b) | rowlow(8b)<<18 ; writes land in ~32B runs per (tile,bucket)
__global__ __launch_bounds__(256) void phase_a(const int* __restrict__ rows,
                                               const int* __restrict__ cols,
                                               int* __restrict__ bCur,
                                               int* __restrict__ entA, int nE) {
    __shared__ int cnt[NB];
    __shared__ int base[NB];
    const int tid = threadIdx.x;
    for (int b = tid; b < NB; b += 256) cnt[b] = 0;
    __syncthreads();
    const int tb = blockIdx.x * TILE;
    const int te = min(tb + TILE, nE);
    for (int e = tb + tid; e < te; e += 256) atomicAdd(&cnt[rows[e] >> 8], 1);
    __syncthreads();
    for (int b = tid; b < NB; b += 256) {
        const int c = cnt[b];
        if (c) base[b] = atomicAdd(&bCur[b], c);
        cnt[b] = 0;
    }
    __syncthreads();
    for (int e = tb + tid; e < te; e += 256) {
        const int r = rows[e];
        const int b = r >> 8;
        const int rank = atomicAdd(&cnt[b], 1);
        entA[base[b] + rank] = cols[e] | ((r & (RB - 1)) << 18);
    }
}

// ---------------- build: phase B — in-LDS row sort per bucket + P + dis ----------------
__global__ __launch_bounds__(256) void phase_b(const int* __restrict__ entA,
                                               const int* __restrict__ bStart,
                                               int* __restrict__ ccol,
                                               int* __restrict__ P,
                                               float* __restrict__ dis) {
    __shared__ int cnt2[RB];
    __shared__ int sc[RB];
    __shared__ int cur[RB];
    __shared__ int srt[CAP];
    const int b   = blockIdx.x;
    const int tid = threadIdx.x;   // blockDim == RB == 256
    const int beg = bStart[b], end = bStart[b + 1];
    const int n   = end - beg;
    cnt2[tid] = 0;
    __syncthreads();
    for (int i = tid; i < n; i += 256) atomicAdd(&cnt2[entA[beg + i] >> 18], 1);
    __syncthreads();
    const int v = cnt2[tid];
    sc[tid] = v;
    __syncthreads();
    int incl = v;
    for (int s = 1; s < 256; s <<= 1) {
        const int add = (tid >= s) ? sc[tid - s] : 0;
        __syncthreads();
        incl += add;
        sc[tid] = incl;
        __syncthreads();
    }
    cur[tid] = incl - v;                    // exclusive offset within bucket
    const int row = b * RB + tid;
    if (row < NTOT) {
        P[row]   = beg + incl;              // end offset of row (start = P[row-1])
        dis[row] = 1.0f / sqrtf((float)v + 1e-9f);
    }
    __syncthreads();
    if (n <= CAP) {
        for (int i = tid; i < n; i += 256) {
            const int e = entA[beg + i];
            const int pos = atomicAdd(&cur[e >> 18], 1);
            srt[pos] = e & 0x3FFFF;
        }
        __syncthreads();
        for (int i = tid; i < n; i += 256) ccol[beg + i] = srt[i];
    } else {                                // statistical never; correctness backstop
        for (int i = tid; i < n; i += 256) {
            const int e = entA[beg + i];
            const int pos = atomicAdd(&cur[e >> 18], 1);
            ccol[beg + pos] = e & 0x3FFFF;
        }
    }
}

// ---------------- SpMM: one wave per row, no atomics, weights = dis[c] (*dis[r]) ----------------
__global__ __launch_bounds__(256) void spmm_csr(const float* __restrict__ x,
                                                const int* __restrict__ P,
                                                const int* __restrict__ ccol,
                                                const float* __restrict__ dis,
                                                float* __restrict__ y) {
    const int lane = threadIdx.x & 63;
    const int wid  = blockIdx.x * 4 + (threadIdx.x >> 6);
    if (wid >= NTOT) return;
    const int beg = (wid == 0) ? 0 : P[wid - 1];
    const int end = P[wid];
    float acc = 0.f;
    int e = beg;
    for (; e + 8 <= end; e += 8) {          // unroll-8: 8 gathers in flight
        int c[8]; float w[8], xv[8];
        #pragma unroll
        for (int k = 0; k < 8; ++k) c[k] = ccol[e + k];
        #pragma unroll
        for (int k = 0; k < 8; ++k) w[k] = dis[c[k]];
        #pragma unroll
        for (int k = 0; k < 8; ++k) xv[k] = x[(size_t)c[k] * DIM + lane];
        #pragma unroll
        for (int k = 0; k < 8; ++k) acc += w[k] * xv[k];
    }
    for (; e < end; ++e) {
        const int c = ccol[e];
        acc += dis[c] * x[(size_t)c * DIM + lane];
    }
    acc *= dis[wid];
    y[(size_t)wid * DIM + lane] = acc;
}

// layer-3: only the 12,288 sampled rows, fused with final accumulate + /4
__global__ __launch_bounds__(256) void spmm_rows_out(const float* __restrict__ x,
                                                     const int* __restrict__ P,
                                                     const int* __restrict__ ccol,
                                                     const float* __restrict__ dis,
                                                     const int* __restrict__ users,
                                                     const int* __restrict__ pos,
                                                     const int* __restrict__ neg,
                                                     float* __restrict__ out) {
    const int lane = threadIdx.x & 63;
    const int wid  = blockIdx.x * 4 + (threadIdx.x >> 6);
    if (wid >= 3 * BATCH) return;
    const int s = wid / BATCH;
    const int j = wid - s * BATCH;
    const int row = (s == 0) ? users[j] : (s == 1) ? pos[j] + N_USERS : neg[j] + N_USERS;
    const int beg = (row == 0) ? 0 : P[row - 1];
    const int end = P[row];
    float acc = 0.f;
    int e = beg;
    for (; e + 4 <= end; e += 4) {
        int c[4]; float w[4], xv[4];
        #pragma unroll
        for (int k = 0; k < 4; ++k) c[k] = ccol[e + k];
        #pragma unroll
        for (int k = 0; k < 4; ++k) w[k] = dis[c[k]];
        #pragma unroll
        for (int k = 0; k < 4; ++k) xv[k] = x[(size_t)c[k] * DIM + lane];
        #pragma unroll
        for (int k = 0; k < 4; ++k) acc += w[k] * xv[k];
    }
    for (; e < end; ++e) {
        const int c = ccol[e];
        acc += dis[c] * x[(size_t)c * DIM + lane];
    }
    acc *= dis[row];
    const size_t o = (size_t)(s * BATCH + j) * DIM + lane;
    out[o] = (out[o] + acc) * 0.25f;
}

// ---------------- atomic-scatter fallback (small-ws safety) ----------------
__global__ void spmm_scatter(const float* __restrict__ x, const int* __restrict__ rows,
                             const int* __restrict__ cols, const float* __restrict__ vals,
                             float* __restrict__ y, int nE) {
    const int lane = threadIdx.x & 63;
    const int wid  = blockIdx.x * (blockDim.x >> 6) + (threadIdx.x >> 6);
    const int nw   = gridDim.x * (blockDim.x >> 6);
    for (int e = wid; e < nE; e += nw)
        atomicAdd(&y[(size_t)rows[e] * DIM + lane], vals[e] * x[(size_t)cols[e] * DIM + lane]);
}

// ---------------- output assembly ----------------
__global__ void init_out(const float* __restrict__ emb, const int* __restrict__ users,
                         const int* __restrict__ pos, const int* __restrict__ neg,
                         float* __restrict__ out) {
    const int t = blockIdx.x * blockDim.x + threadIdx.x;
    const int lane = t & 63;
    const int w = t >> 6;
    if (w >= 3 * BATCH) return;
    const int s = w / BATCH;
    const int j = w - s * BATCH;
    const int row = (s == 0) ? users[j] : (s == 1) ? pos[j] + N_USERS : neg[j] + N_USERS;
    const float v = emb[(size_t)row * DIM + lane];
    out[(size_t)(s * BATCH + j) * DIM + lane] = v;        // final_* accumulator (layer 0)
    out[(size_t)((s + 3) * BATCH + j) * DIM + lane] = v;  // init_* output
}

__global__ void gather_addscale(const float* __restrict__ e, const int* __restrict__ users,
                                const int* __restrict__ pos, const int* __restrict__ neg,
                                float* __restrict__ out, float scale) {
    const int t = blockIdx.x * blockDim.x + threadIdx.x;
    const int lane = t & 63;
    const int w = t >> 6;
    if (w >= 3 * BATCH) return;
    const int s = w / BATCH;
    const int j = w - s * BATCH;
    const int row = (s == 0) ? users[j] : (s == 1) ? pos[j] + N_USERS : neg[j] + N_USERS;
    const size_t o = (size_t)(s * BATCH + j) * DIM + lane;
    out[o] = (out[o] + e[(size_t)row * DIM + lane]) * scale;
}

// ---------------- host ----------------
extern "C" void kernel_launch(void* const* d_in, const int* in_sizes, int n_in,
                              void* d_out, int out_size, void* d_ws, size_t ws_size,
                              hipStream_t stream) {
    const float* emb  = (const float*)d_in[0];
    const int*   rows = (const int*)d_in[1];
    const int*   cols = (const int*)d_in[2];
    const float* vals = (const float*)d_in[3];
    const int*   users = (const int*)d_in[4];
    const int*   pos   = (const int*)d_in[5];
    const int*   neg   = (const int*)d_in[6];
    float* out = (float*)d_out;

    const int nE = in_sizes[1];
    auto rup = [](size_t x) { return (x + 255) & ~(size_t)255; };
    const size_t szBuf = rup((size_t)NTOT * DIM * sizeof(float));   // 64 MB
    const size_t szCol = rup((size_t)nE * sizeof(int));             // 16 MB
    const size_t szP   = rup((size_t)NTOT * sizeof(int));           // 1 MB
    const size_t szDis = rup((size_t)NTOT * sizeof(float));         // 1 MB
    const size_t szBk  = rup((size_t)(NB + 1) * sizeof(int));

    char* w = (char*)d_ws;
    float* bufA = (float*)w; w += szBuf;
    float* bufB = (float*)w; w += szBuf;
    int* entA   = (int*)bufB;              // phase-A entries alias bufB (dead before spmm-2)
    int*   ccol = (int*)w;   w += szCol;
    int*   P    = (int*)w;   w += szP;
    float* dis  = (float*)w; w += szDis;
    int* bCnt   = (int*)w;   w += szBk;
    int* bStart = (int*)w;   w += szBk;
    int* bCur   = (int*)w;   w += szBk;
    const size_t need = (size_t)((char*)w - (char*)d_ws);

    const int gatherBlocks = (3 * BATCH * DIM + 255) / 256;

    init_out<<<gatherBlocks, 256, 0, stream>>>(emb, users, pos, neg, out);

    if (ws_size >= need && nE > 0) {
        // ---- build bucketed CSR (coalesced two-phase counting sort) ----
        hipMemsetAsync(bCnt, 0, (size_t)NB * sizeof(int), stream);
        coarse_hist<<<512, 256, 0, stream>>>(rows, bCnt, nE);
        bucket_scan<<<1, 1024, 0, stream>>>(bCnt, bStart, bCur);
        const int nTiles = (nE + TILE - 1) / TILE;
        phase_a<<<nTiles, 256, 0, stream>>>(rows, cols, bCur, entA, nE);
        phase_b<<<NB, 256, 0, stream>>>(entA, bStart, ccol, P, dis);

        const int spmmBlocks = (NTOT + 3) / 4;
        // layers 1,2: full SpMM
        spmm_csr<<<spmmBlocks, 256, 0, stream>>>(emb,  P, ccol, dis, bufA);
        gather_addscale<<<gatherBlocks, 256, 0, stream>>>(bufA, users, pos, neg, out, 1.0f);
        spmm_csr<<<spmmBlocks, 256, 0, stream>>>(bufA, P, ccol, dis, bufB);
        gather_addscale<<<gatherBlocks, 256, 0, stream>>>(bufB, users, pos, neg, out, 1.0f);
        // layer 3: only sampled rows, fused accumulate + /4
        const int rowsBlocks = (3 * BATCH + 3) / 4;
        spmm_rows_out<<<rowsBlocks, 256, 0, stream>>>(bufB, P, ccol, dis, users, pos, neg, out);
    } else {
        // ---- atomic fallback ----
        const size_t bufBytes = (size_t)NTOT * DIM * sizeof(float);
        hipMemsetAsync(bufA, 0, bufBytes, stream);
        spmm_scatter<<<2048, 256, 0, stream>>>(emb, rows, cols, vals, bufA, nE);
        gather_addscale<<<gatherBlocks, 256, 0, stream>>>(bufA, users, pos, neg, out, 1.0f);
        hipMemsetAsync(bufB, 0, bufBytes, stream);
        spmm_scatter<<<2048, 256, 0, stream>>>(bufA, rows, cols, vals, bufB, nE);
        gather_addscale<<<gatherBlocks, 256, 0, stream>>>(bufB, users, pos, neg, out, 1.0f);
        hipMemsetAsync(bufA, 0, bufBytes, stream);
        spmm_scatter<<<2048, 256, 0, stream>>>(bufB, rows, cols, vals, bufA, nE);
        gather_addscale<<<gatherBlocks, 256, 0, stream>>>(bufA, users, pos, neg, out, 0.25f);
    }
}